// Round 1
// baseline (141.860 us; speedup 1.0000x reference)
//
#include <hip/hip_runtime.h>
#include <math.h>

// B=16384 rows, C=1000 cols, fp32. One wave (64 lanes) per row, 4 rows per
// 256-thread block. Row = 250 float4 per input; lane l holds float4 indices
// l+64c (c=0..3) => 16 scalar elements per input, register-resident so the
// second pass re-reads registers, not HBM. Memory-bound: 131 MB total.

constexpr int kC  = 1000;
constexpr int kNV = kC / 4;        // 250 float4 per row
constexpr int kRowsPerBlock = 4;   // 4 waves per block

__global__ __launch_bounds__(256) void netsat_kernel(
    const float* __restrict__ y1, const float* __restrict__ y2,
    float* __restrict__ out, int nrows)
{
    const int lane = threadIdx.x & 63;
    const int wave = threadIdx.x >> 6;
    const int row  = blockIdx.x * kRowsPerBlock + wave;
    if (row >= nrows) return;

    const float4* r1 = reinterpret_cast<const float4*>(y1) + (size_t)row * kNV;
    const float4* r2 = reinterpret_cast<const float4*>(y2) + (size_t)row * kNV;

    float4 a[4], b[4];
    const float4 ninf4 = make_float4(-INFINITY, -INFINITY, -INFINITY, -INFINITY);
#pragma unroll
    for (int c = 0; c < 4; ++c) {
        const int vi = lane + 64 * c;
        if (vi < kNV) { a[c] = r1[vi]; b[c] = r2[vi]; }
        else          { a[c] = ninf4;  b[c] = ninf4; }
    }

    // ---- pass 1: per-lane top-2 (+argmax of top-1) for both inputs ----
    float m1 = -INFINITY, m2 = -INFINITY; int i1 = 0x7fffffff;
    float n1 = -INFINITY, n2 = -INFINITY; int j1 = 0x7fffffff;
#pragma unroll
    for (int c = 0; c < 4; ++c) {
        const float* av = reinterpret_cast<const float*>(&a[c]);
        const float* bv = reinterpret_cast<const float*>(&b[c]);
#pragma unroll
        for (int k = 0; k < 4; ++k) {
            const int j = 4 * (lane + 64 * c) + k;
            const float v = av[k];
            if (v > m1)      { m2 = m1; m1 = v; i1 = j; }
            else if (v > m2) { m2 = v; }
            const float w = bv[k];
            if (w > n1)      { n2 = n1; n1 = w; j1 = j; }
            else if (w > n2) { n2 = w; }
        }
    }

    // ---- butterfly top-2 reduce across the wave (all lanes converge) ----
#pragma unroll
    for (int off = 32; off > 0; off >>= 1) {
        const float om1 = __shfl_xor(m1, off, 64);
        const float om2 = __shfl_xor(m2, off, 64);
        const int   oi1 = __shfl_xor(i1, off, 64);
        if (om1 > m1 || (om1 == m1 && oi1 < i1)) {
            m2 = fmaxf(m1, om2); m1 = om1; i1 = oi1;
        } else {
            m2 = fmaxf(m2, om1);
        }
        const float on1 = __shfl_xor(n1, off, 64);
        const float on2 = __shfl_xor(n2, off, 64);
        const int   oj1 = __shfl_xor(j1, off, 64);
        if (on1 > n1 || (on1 == n1 && oj1 < j1)) {
            n2 = fmaxf(n1, on2); n1 = on1; j1 = oj1;
        } else {
            n2 = fmaxf(n2, on1);
        }
    }

    // ---- pass 2: max_j min(a - loo1, b - loo2) over register values ----
    float best = -INFINITY;
#pragma unroll
    for (int c = 0; c < 4; ++c) {
        const float* av = reinterpret_cast<const float*>(&a[c]);
        const float* bv = reinterpret_cast<const float*>(&b[c]);
#pragma unroll
        for (int k = 0; k < 4; ++k) {
            const int j = 4 * (lane + 64 * c) + k;
            const float l1 = (j == i1) ? m2 : m1;
            const float l2 = (j == j1) ? n2 : n1;
            best = fmaxf(best, fminf(av[k] - l1, bv[k] - l2));
        }
    }
#pragma unroll
    for (int off = 32; off > 0; off >>= 1)
        best = fmaxf(best, __shfl_xor(best, off, 64));

    if (lane == 0) out[row] = best;
}

extern "C" void kernel_launch(void* const* d_in, const int* in_sizes, int n_in,
                              void* d_out, int out_size, void* d_ws, size_t ws_size,
                              hipStream_t stream) {
    const float* y1 = (const float*)d_in[0];
    const float* y2 = (const float*)d_in[1];
    float* out = (float*)d_out;
    const int nrows = out_size;  // 16384
    const int blocks = (nrows + kRowsPerBlock - 1) / kRowsPerBlock;
    netsat_kernel<<<blocks, 256, 0, stream>>>(y1, y2, out, nrows);
}